// Round 1
// baseline (85.428 us; speedup 1.0000x reference)
//
#include <hip/hip_runtime.h>
#include <math.h>

#define BATCH 384
#define FEAT 256
#define NUM_ID 48
#define GROUP 8
// ANNEAL = 0.01 -> 1/temp = 100

__device__ __forceinline__ float temp_sigmoid_from_diff(float diff) {
    // reference: exponent = clip(-t/temp, -50, 50); 1/(1+exp(exponent))
    float e = -100.0f * diff;
    e = fminf(fmaxf(e, -50.0f), 50.0f);
    return 1.0f / (1.0f + expf(e));
}

// One block per row (768 rows total: 384 preds + 384 gallery), 256 threads = FEAT.
__global__ __launch_bounds__(256) void normalize_kernel(
    const float* __restrict__ preds, const float* __restrict__ gallery,
    float* __restrict__ pn, float* __restrict__ gn,
    float* accum, unsigned int* counter)
{
    int row = blockIdx.x;
    int t = threadIdx.x;
    const float* src;
    float* dst;
    if (row < BATCH) { src = preds + row * FEAT;          dst = pn + row * FEAT; }
    else             { src = gallery + (row - BATCH) * FEAT; dst = gn + (row - BATCH) * FEAT; }

    float x = src[t];
    float ss = x * x;
    #pragma unroll
    for (int m = 32; m >= 1; m >>= 1) ss += __shfl_xor(ss, m, 64);
    __shared__ float part[4];
    if ((t & 63) == 0) part[t >> 6] = ss;
    __syncthreads();
    float total = part[0] + part[1] + part[2] + part[3];
    float norm = sqrtf(total);
    float scale = 1.0f / fmaxf(norm, 1e-12f);
    dst[t] = x * scale;

    if (row == 0 && t == 0) { *accum = 0.0f; *counter = 0u; }
}

// One block per row i of sim_all. Computes sim row, block-diagonal rk, pos_rk,
// and accumulates sum_b pos_rk[b]/rk[b] into *accum. Last block finalizes out.
__global__ __launch_bounds__(256) void smoothap_kernel(
    const float* __restrict__ pn, const float* __restrict__ gn,
    float* accum, unsigned int* counter, float* __restrict__ out)
{
    __shared__ float p_row[FEAT];
    __shared__ float s[BATCH];
    __shared__ float rk[GROUP];
    __shared__ float part[4][GROUP];

    int i = blockIdx.x;
    int t = threadIdx.x;

    p_row[t] = pn[i * FEAT + t];
    __syncthreads();

    // sim row: s[k] = dot(p_row, g[k])
    for (int k = t; k < BATCH; k += 256) {
        const float* grow = gn + k * FEAT;
        float acc = 0.0f;
        #pragma unroll 8
        for (int d = 0; d < FEAT; d += 4) {
            float4 gv = *(const float4*)(grow + d);
            acc += p_row[d] * gv.x + p_row[d + 1] * gv.y
                 + p_row[d + 2] * gv.z + p_row[d + 3] * gv.w;
        }
        s[k] = acc;
    }
    __syncthreads();

    int base = (i >> 3) * GROUP;  // start of this id's block

    // rk[b] = sum_k sigmoid_t(s[k] - s[base+b])
    float acc8[GROUP];
    #pragma unroll
    for (int b = 0; b < GROUP; b++) acc8[b] = 0.0f;
    for (int k = t; k < BATCH; k += 256) {
        float sk = s[k];
        #pragma unroll
        for (int b = 0; b < GROUP; b++)
            acc8[b] += temp_sigmoid_from_diff(sk - s[base + b]);
    }
    #pragma unroll
    for (int b = 0; b < GROUP; b++) {
        float v = acc8[b];
        #pragma unroll
        for (int m = 32; m >= 1; m >>= 1) v += __shfl_xor(v, m, 64);
        acc8[b] = v;
    }
    if ((t & 63) == 0) {
        #pragma unroll
        for (int b = 0; b < GROUP; b++) part[t >> 6][b] = acc8[b];
    }
    __syncthreads();
    if (t < GROUP) rk[t] = part[0][t] + part[1][t] + part[2][t] + part[3][t];
    __syncthreads();

    // pos part on wave 0: lane = 8*b + c
    if (t < 64) {
        int b = t >> 3, c = t & 7;
        float v = temp_sigmoid_from_diff(s[base + c] - s[base + b]);
        v += __shfl_xor(v, 1, 64);
        v += __shfl_xor(v, 2, 64);
        v += __shfl_xor(v, 4, 64);   // all 8 lanes of group b now hold pos_rk[b]
        float contrib = (c == 0) ? (v / rk[b]) : 0.0f;
        contrib += __shfl_xor(contrib, 8, 64);
        contrib += __shfl_xor(contrib, 16, 64);
        contrib += __shfl_xor(contrib, 32, 64); // lane 0: sum_b pos_rk[b]/rk[b]
        if (t == 0) {
            atomicAdd(accum, contrib);
            __threadfence();
            unsigned int old = atomicAdd(counter, 1u);
            if (old == (unsigned)(BATCH - 1)) {
                float total = atomicAdd(accum, 0.0f);  // read final value
                out[0] = 1.0f - total / (float)(GROUP * BATCH);
            }
        }
    }
}

extern "C" void kernel_launch(void* const* d_in, const int* in_sizes, int n_in,
                              void* d_out, int out_size, void* d_ws, size_t ws_size,
                              hipStream_t stream) {
    const float* preds   = (const float*)d_in[0];
    const float* gallery = (const float*)d_in[1];
    float* out = (float*)d_out;

    float* ws = (float*)d_ws;
    float* accum = ws;                                   // 1 float
    unsigned int* counter = (unsigned int*)(ws + 1);     // 1 uint
    float* pn = ws + 16;                                 // 384*256 floats (64B aligned)
    float* gn = pn + BATCH * FEAT;                       // 384*256 floats

    normalize_kernel<<<2 * BATCH, 256, 0, stream>>>(preds, gallery, pn, gn, accum, counter);
    smoothap_kernel<<<BATCH, 256, 0, stream>>>(pn, gn, accum, counter, out);
}

// Round 2
// 80.846 us; speedup vs baseline: 1.0567x; 1.0567x over previous
//
#include <hip/hip_runtime.h>
#include <math.h>

#define BATCH 384
#define FEAT 256
#define GROUP 8
// ANNEAL = 0.01 -> 1/temp = 100

__device__ __forceinline__ float temp_sigmoid_from_diff(float diff) {
    // reference: exponent = clip(-t/temp, -50, 50); 1/(1+exp(exponent))
    float e = fminf(fmaxf(-100.0f * diff, -50.0f), 50.0f);
    return 1.0f / (1.0f + __expf(e));
}

// One block per row i. Normalizes p row in-block, computes the full sim row
// (with gallery norms fused into the dot loop), the block-diagonal rank sums,
// the positive-pair rank sums, and writes sum_b pos_rk[b]/rk[b] to partials[i].
__global__ __launch_bounds__(256) void smoothap_main(
    const float* __restrict__ preds, const float* __restrict__ gallery,
    float* __restrict__ partials)
{
    __shared__ float p_row[FEAT];
    __shared__ float s[BATCH];
    __shared__ float rk[GROUP];
    __shared__ float red4[4];
    __shared__ float part[4][GROUP];

    const int i = blockIdx.x;
    const int t = threadIdx.x;

    // ---- normalize preds row i into LDS ----
    float x = preds[i * FEAT + t];
    float ssq = x * x;
    #pragma unroll
    for (int m = 32; m >= 1; m >>= 1) ssq += __shfl_xor(ssq, m, 64);
    if ((t & 63) == 0) red4[t >> 6] = ssq;
    __syncthreads();
    float ptot = red4[0] + red4[1] + red4[2] + red4[3];
    p_row[t] = x / fmaxf(sqrtf(ptot), 1e-12f);
    __syncthreads();

    // ---- sim row: s[k] = dot(p_hat, g_k) / max(||g_k||, eps) ----
    for (int k = t; k < BATCH; k += 256) {
        const float* g = gallery + k * FEAT;
        float d0 = 0.0f, d1 = 0.0f, q0 = 0.0f, q1 = 0.0f;
        #pragma unroll 8
        for (int d = 0; d < FEAT; d += 8) {
            float4 a = *(const float4*)(g + d);
            float4 b = *(const float4*)(g + d + 4);
            d0 += p_row[d]     * a.x + p_row[d + 1] * a.y
                + p_row[d + 2] * a.z + p_row[d + 3] * a.w;
            d1 += p_row[d + 4] * b.x + p_row[d + 5] * b.y
                + p_row[d + 6] * b.z + p_row[d + 7] * b.w;
            q0 += a.x * a.x + a.y * a.y + a.z * a.z + a.w * a.w;
            q1 += b.x * b.x + b.y * b.y + b.z * b.z + b.w * b.w;
        }
        s[k] = (d0 + d1) / fmaxf(sqrtf(q0 + q1), 1e-12f);
    }
    __syncthreads();

    const int base = (i >> 3) * GROUP;  // start of this id's diagonal block

    // ---- rk[b] = sum_k sigmoid_t(s[k] - s[base+b]) ----
    float acc8[GROUP];
    #pragma unroll
    for (int b = 0; b < GROUP; b++) acc8[b] = 0.0f;
    for (int k = t; k < BATCH; k += 256) {
        float sk = s[k];
        #pragma unroll
        for (int b = 0; b < GROUP; b++)
            acc8[b] += temp_sigmoid_from_diff(sk - s[base + b]);
    }
    #pragma unroll
    for (int b = 0; b < GROUP; b++) {
        float v = acc8[b];
        #pragma unroll
        for (int m = 32; m >= 1; m >>= 1) v += __shfl_xor(v, m, 64);
        acc8[b] = v;
    }
    if ((t & 63) == 0) {
        #pragma unroll
        for (int b = 0; b < GROUP; b++) part[t >> 6][b] = acc8[b];
    }
    __syncthreads();
    if (t < GROUP) rk[t] = part[0][t] + part[1][t] + part[2][t] + part[3][t];
    __syncthreads();

    // ---- pos part on wave 0: lane = 8*b + c ----
    if (t < 64) {
        int b = t >> 3, c = t & 7;
        float v = temp_sigmoid_from_diff(s[base + c] - s[base + b]);
        v += __shfl_xor(v, 1, 64);
        v += __shfl_xor(v, 2, 64);
        v += __shfl_xor(v, 4, 64);   // lanes of group b hold pos_rk[b]
        float contrib = (c == 0) ? (v / rk[b]) : 0.0f;
        contrib += __shfl_xor(contrib, 8, 64);
        contrib += __shfl_xor(contrib, 16, 64);
        contrib += __shfl_xor(contrib, 32, 64);
        if (t == 0) partials[i] = contrib;   // unconditional write -> poison-safe
    }
}

// Single block: sum 384 partials, finalize.
__global__ __launch_bounds__(256) void smoothap_finalize(
    const float* __restrict__ partials, float* __restrict__ out)
{
    __shared__ float red4[4];
    const int t = threadIdx.x;
    float v = partials[t];
    if (t < BATCH - 256) v += partials[t + 256];
    #pragma unroll
    for (int m = 32; m >= 1; m >>= 1) v += __shfl_xor(v, m, 64);
    if ((t & 63) == 0) red4[t >> 6] = v;
    __syncthreads();
    if (t == 0)
        out[0] = 1.0f - (red4[0] + red4[1] + red4[2] + red4[3])
                        / (float)(GROUP * BATCH);
}

extern "C" void kernel_launch(void* const* d_in, const int* in_sizes, int n_in,
                              void* d_out, int out_size, void* d_ws, size_t ws_size,
                              hipStream_t stream) {
    const float* preds   = (const float*)d_in[0];
    const float* gallery = (const float*)d_in[1];
    float* out = (float*)d_out;
    float* partials = (float*)d_ws;   // 384 floats, fully overwritten every call

    smoothap_main<<<BATCH, 256, 0, stream>>>(preds, gallery, partials);
    smoothap_finalize<<<1, 256, 0, stream>>>(partials, out);
}